// Round 1
// 1319.678 us; speedup vs baseline: 1.5969x; 1.5969x over previous
//
#include <hip/hip_runtime.h>
#include <math.h>
#include <float.h>

constexpr int N = 128;
constexpr int V = 50257;
constexpr int H = 4096;
constexpr int L = 200;

// ---------------- GEMM tiling ----------------
constexpr int BN = 64;            // v-cols per block
constexpr int BK = 32;            // k per step
constexpr int NSTEP = H / BK;     // 128
// LDS per buffer: A tile 128x32 (hi+lo bf16 interleaved, 8x16B chunks/row) = 16 KB
//                 B tile 64x32 f32 (8x16B chunks/row)                      =  8 KB
constexpr int A_BYTES = 16384;
constexpr int B_BYTES = 8192;
constexpr int BUF_BYTES = A_BYTES + B_BYTES;   // 24576; x2 = 48 KB -> 3 blocks/CU

constexpr int NB1 = 1024;             // coarse bins
constexpr int NB2 = 1024;             // fine bins (within boundary coarse bin)
constexpr float RANGE = 48.0f;        // covers (rowmax - logit) span with margin
constexpr float W1 = RANGE / (float)NB1;          // 0.046875 (exact)
constexpr float INV_W1 = (float)NB1 / RANGE;
constexpr float INV_W2 = (float)NB1 * (float)NB2 / RANGE;
constexpr int XCAP = 2048;            // coarse boundary-bin candidate capacity
constexpr int XCAP2 = 256;            // fine boundary-bin candidate capacity

using short8 = __attribute__((ext_vector_type(8))) short;  // 8 bf16
using f32x4  = __attribute__((ext_vector_type(4))) float;

struct RowStats { float m, tstar, Z; int bstar, fstar, istar; int pad[2]; };  // 32 B

// binning helpers -- MUST be bit-identical between select & final
__device__ __forceinline__ int bin1_of(float m, float x) {
  int b = (int)((m - x) * INV_W1);
  return b < 0 ? 0 : (b > NB1 - 1 ? NB1 - 1 : b);
}
__device__ __forceinline__ float hi2_of(float m, int bstar) {
  return __fmaf_rn((float)bstar, -W1, m);     // forced fma: identical in both kernels
}
__device__ __forceinline__ int bin2_of(float hi2, float x) {
  int b = (int)((hi2 - x) * INV_W2);
  return b < 0 ? 0 : (b > NB2 - 1 ? NB2 - 1 : b);
}

// async 16-B global -> LDS copy (wave-uniform LDS base + lane*16 by construction)
__device__ __forceinline__ void gl_lds16(const void* g, void* l) {
  __builtin_amdgcn_global_load_lds(
      (const __attribute__((address_space(1))) unsigned int*)g,
      (__attribute__((address_space(3))) unsigned int*)l, 16, 0, 0);
}

// ---------------- prep: write A as the pre-swizzled packed LDS image ----------------
// For k-step t (0..127), record idx (0..1023): row = idx>>3, chunk c = idx&7.
// LDS chunk c of row holds *global* chunk g = c ^ (row&7), where g<4 -> bf16-hi of
// A[row][t*32 + g*8 .. +8), g>=4 -> bf16-lo of A[row][t*32 + (g&3)*8 .. +8).
// GEMM staging of A is then a perfectly linear 16-B copy (rule #21 compliant).
__global__ __launch_bounds__(256)
void sampler_prep(const float* __restrict__ A, ushort* __restrict__ Apk)
{
  int gid = blockIdx.x * 256 + threadIdx.x;   // 0 .. NSTEP*1024-1
  int t   = gid >> 10;
  int idx = gid & 1023;
  int row = idx >> 3;
  int c   = idx & 7;
  int g   = c ^ (row & 7);
  const float* src = A + (size_t)row * H + t * BK + (g & 3) * 8;
  short8 o;
#pragma unroll
  for (int j = 0; j < 8; j++) {
    float x = src[j];
    uint b = __float_as_uint(x);
    if (g < 4) {
      o[j] = (short)(b >> 16);                            // truncated bf16 hi
    } else {
      float hif = __uint_as_float(b & 0xFFFF0000u);
      o[j] = (short)(__float_as_uint(x - hif) >> 16);     // bf16 lo (x - hi exact)
    }
  }
  *(short8*)(Apk + (size_t)gid * 8) = o;
}

// split 8 f32 -> bf16 hi/lo (truncation), identical math to prep
__device__ __forceinline__ void split8v(const f32x4& f0, const f32x4& f1,
                                        short8& hi, short8& lo) {
  float xx[8] = {f0[0], f0[1], f0[2], f0[3], f1[0], f1[1], f1[2], f1[3]};
#pragma unroll
  for (int j = 0; j < 8; j++) {
    uint bb = __float_as_uint(xx[j]);
    hi[j] = (short)(bb >> 16);
    float hif = __uint_as_float(bb & 0xFFFF0000u);
    lo[j] = (short)(__float_as_uint(xx[j] - hif) >> 16);
  }
}

// ---------------- GEMM: LDS double-buffered, async-staged, 2-phase ----------------
// Block: 128(M) x 64(N), BK=32. 4 waves as 2M x 2N; wave tile 64x32 (4mt x 2nt).
// Split-bf16 fp32 emulation: (Ah+Al)(Bh+Bl) ~ AhBh + AhBl + AlBh (3 MFMAs/tile).
// LDS rows are 128 B = 8 x 16B chunks, chunk-swizzled by XOR(row&7) so each
// quarter-wave's ds_read_b128 hits 8 distinct chunk slots (min-aliasing).
__global__ __launch_bounds__(256, 3)
void sampler_gemm(const ushort* __restrict__ Apk, const float* __restrict__ B,
                  const float* __restrict__ temps, float* __restrict__ out)
{
  __shared__ __align__(16) char lds[2][BUF_BYTES];

  const int tid  = threadIdx.x;
  const int wave = tid >> 6, lane = tid & 63;
  const int cc   = lane & 15, quad = lane >> 4;
  const int wm   = wave >> 1, wn = wave & 1;
  const int v0   = blockIdx.x * BN;
  const int s7   = cc & 7;

  // ---- staging sources (per-thread, constant except k-step advance) ----
  const ushort* aS = Apk + (size_t)tid * 8;          // + i*2048 + t*8192 (ushorts)
  const float* bS[2];
#pragma unroll
  for (int i = 0; i < 2; i++) {
    int idx = i * 256 + tid;
    int row = idx >> 3, ch = idx & 7;
    int vv = v0 + row; vv = vv < V ? vv : V - 1;     // clamp OOB rows of last block
    bS[i] = B + (size_t)vv * H + ((ch ^ (row & 7)) << 2);  // pre-swizzled source
  }

  // ---- LDS read offsets (swizzled); row&7 == cc&7 for all tiles (16 | tile strides)
  const int aHi = (wm * 64 + cc) * 128 + ((quad ^ s7) << 4);
  const int aLo = (wm * 64 + cc) * 128 + (((4 + quad) ^ s7) << 4);
  const int bO0 = A_BYTES + (wn * 32 + cc) * 128 + (((2 * quad) ^ s7) << 4);
  const int bO1 = A_BYTES + (wn * 32 + cc) * 128 + (((2 * quad + 1) ^ s7) << 4);

  f32x4 acc[4][2];
#pragma unroll
  for (int mt = 0; mt < 4; mt++)
#pragma unroll
    for (int nt = 0; nt < 2; nt++) acc[mt][nt] = (f32x4){0.f, 0.f, 0.f, 0.f};

  auto stage = [&](int t, int sel) {
    char* buf = lds[sel];
    const ushort* a = aS + (size_t)t * 8192;
#pragma unroll
    for (int i = 0; i < 4; i++)                       // A: 16 KB linear copy
      gl_lds16(a + i * 2048, buf + (i * 256 + tid) * 16);
#pragma unroll
    for (int i = 0; i < 2; i++)                       // B: 8 KB, source-swizzled
      gl_lds16(bS[i] + t * BK, buf + A_BYTES + (i * 256 + tid) * 16);
  };

  stage(0, 0);
  __syncthreads();                                    // drain vmcnt -> buf0 ready

#pragma unroll 1
  for (int t = 0; t < NSTEP; ++t) {
    const int sel = t & 1;
    if (t + 1 < NSTEP) stage(t + 1, sel ^ 1);         // prefetch overlaps compute
    const char* buf = lds[sel];

    short8 ah[4], al[4];
    f32x4 b0[2], b1[2];
#pragma unroll
    for (int mt = 0; mt < 4; mt++) {
      ah[mt] = *(const short8*)(buf + aHi + mt * 2048);
      al[mt] = *(const short8*)(buf + aLo + mt * 2048);
    }
#pragma unroll
    for (int nt = 0; nt < 2; nt++) {
      b0[nt] = *(const f32x4*)(buf + bO0 + nt * 2048);
      b1[nt] = *(const f32x4*)(buf + bO1 + nt * 2048);
    }
    short8 bh[2], bl[2];
#pragma unroll
    for (int nt = 0; nt < 2; nt++) split8v(b0[nt], b1[nt], bh[nt], bl[nt]);

#pragma unroll
    for (int mt = 0; mt < 4; mt++)
#pragma unroll
      for (int nt = 0; nt < 2; nt++) {
        acc[mt][nt] = __builtin_amdgcn_mfma_f32_16x16x32_bf16(ah[mt], bh[nt], acc[mt][nt], 0, 0, 0);
        acc[mt][nt] = __builtin_amdgcn_mfma_f32_16x16x32_bf16(ah[mt], bl[nt], acc[mt][nt], 0, 0, 0);
        acc[mt][nt] = __builtin_amdgcn_mfma_f32_16x16x32_bf16(al[mt], bh[nt], acc[mt][nt], 0, 0, 0);
      }
    __syncthreads();                                  // next tile staged + all reads done
  }

  // ---- epilogue: C/D col=lane&15, row=quad*4+reg ----
#pragma unroll
  for (int mt = 0; mt < 4; mt++)
#pragma unroll
    for (int nt = 0; nt < 2; nt++) {
      int v = v0 + wn * 32 + nt * 16 + cc;
      if (v < V) {
#pragma unroll
        for (int r4 = 0; r4 < 4; r4++) {
          int r = wm * 64 + mt * 16 + quad * 4 + r4;
          out[(size_t)r * V + v] = acc[mt][nt][r4] / temps[r];
        }
      }
    }
}

// ---------------- penalties fixup (first-occurrence thread = unique writer) ----------
__global__ __launch_bounds__(256)
void sampler_fixup(float* __restrict__ logits, const int* __restrict__ toks,
                   const float* __restrict__ pres, const float* __restrict__ freq,
                   const float* __restrict__ rep, const float* __restrict__ temps)
{
  int n = blockIdx.x, l = threadIdx.x;
  if (l >= L) return;
  const int* row = toks + n * L;
  int tok = row[l];
  for (int j = 0; j < l; j++)
    if (row[j] == tok) return;
  int cnum = 0;
  for (int j = 0; j < L; j++) cnum += (row[j] == tok) ? 1 : 0;
  float T = temps[n];
  float x = logits[(size_t)n * V + tok];
  float rp = rep[n];
  x = (x > 0.f) ? (x / rp) : (x * rp);
  x -= (freq[n] * (float)cnum + pres[n]) / T;
  logits[(size_t)n * V + tok] = x;
}

// ---------------- select: rowmax + 2-level hist select + exact tie walk -------------
// 512 threads (2 waves/SIMD), 4-way batched global loads for latency hiding.
__global__ __launch_bounds__(512)
void sampler_select(const float* __restrict__ logits, const float* __restrict__ top_ps,
                    const int* __restrict__ top_ks, RowStats* __restrict__ stats)
{
  const int n = blockIdx.x, tid = threadIdx.x;
  const float* __restrict__ xr = logits + (size_t)n * V;
  constexpr int T = 512;
  constexpr int VB = (V / (4 * T)) * (4 * T);   // 49152

  __shared__ unsigned s_cnt[NB1];
  __shared__ float s_esum[NB1];
  __shared__ unsigned s_pc[T];
  __shared__ float s_pe[T];
  __shared__ float s_xl[XCAP];
  __shared__ int s_il[XCAP];
  __shared__ float s_x2[XCAP2];
  __shared__ int s_i2[XCAP2];
  __shared__ int s_bstar, s_fstar;
  __shared__ int s_accA, s_accA2;
  __shared__ float s_accE, s_accE2;
  __shared__ unsigned s_num, s_num2;
  __shared__ float s_m, s_thresh;

  const float P = top_ps[n];
  const int K = top_ks[n];

  // ---- pass 0: row max ----
  float mx = -FLT_MAX;
  for (int v0 = tid; v0 < VB; v0 += 4 * T) {
    float t0 = xr[v0], t1 = xr[v0 + T], t2 = xr[v0 + 2 * T], t3 = xr[v0 + 3 * T];
    mx = fmaxf(mx, fmaxf(fmaxf(t0, t1), fmaxf(t2, t3)));
  }
  for (int v0 = VB + tid; v0 < V; v0 += T) mx = fmaxf(mx, xr[v0]);
  s_pe[tid] = mx; __syncthreads();
  for (int s = T / 2; s > 0; s >>= 1) {
    if (tid < s) s_pe[tid] = fmaxf(s_pe[tid], s_pe[tid + s]);
    __syncthreads();
  }
  if (tid == 0) s_m = s_pe[0];
  __syncthreads();
  const float m = s_m;

  for (int i = tid; i < NB1; i += T) { s_cnt[i] = 0u; s_esum[i] = 0.f; }
  if (tid == 0) { s_bstar = NB1; s_fstar = NB2; s_num = 0u; s_num2 = 0u; }
  __syncthreads();

  // ---- pass 1: coarse histogram (count + expsum) ----
  {
    auto proc = [&](float t) {
      int b = bin1_of(m, t);
      atomicAdd(&s_esum[b], __expf(t - m));
      atomicAdd(&s_cnt[b], 1u);
    };
    for (int v0 = tid; v0 < VB; v0 += 4 * T) {
      float t0 = xr[v0], t1 = xr[v0 + T], t2 = xr[v0 + 2 * T], t3 = xr[v0 + 3 * T];
      proc(t0); proc(t1); proc(t2); proc(t3);
    }
    for (int v0 = VB + tid; v0 < V; v0 += T) proc(xr[v0]);
  }
  __syncthreads();

  // inclusive prefix over NB1 bins: 2 bins/thread + T-wide scan
  {
    const int base = tid * (NB1 / T);
    unsigned pc = 0; float pe = 0.f;
#pragma unroll
    for (int j = 0; j < NB1 / T; j++) { pc += s_cnt[base + j]; pe += s_esum[base + j]; }
    s_pc[tid] = pc; s_pe[tid] = pe;
    __syncthreads();
    for (int off = 1; off < T; off <<= 1) {
      unsigned cp = 0; float ep = 0.f;
      if (tid >= off) { cp = s_pc[tid - off]; ep = s_pe[tid - off]; }
      __syncthreads();
      s_pc[tid] += cp; s_pe[tid] += ep;
      __syncthreads();
    }
    if (tid == 0) s_thresh = P * s_pe[T - 1];
    __syncthreads();
    const float thresh = s_thresh;

    // first bin where inclusive count > K or inclusive expsum > thresh (monotone)
    int ca = (int)(tid ? s_pc[tid - 1] : 0u);
    float ea = tid ? s_pe[tid - 1] : 0.f;
    int found = NB1;
#pragma unroll
    for (int j = 0; j < NB1 / T; j++) {
      int cb = (int)s_cnt[base + j]; float eb = s_esum[base + j];
      if ((ca + cb > K) || (ea + eb > thresh)) { found = base + j; break; }
      ca += cb; ea += eb;
    }
    if (found < NB1) atomicMin(&s_bstar, found);
    __syncthreads();
    const int bstar = s_bstar;      // always < NB1 (count at last bin = V > K)
    if (tid == (bstar / (NB1 / T))) {
      int ca2 = (int)(tid ? s_pc[tid - 1] : 0u);
      float ea2 = tid ? s_pe[tid - 1] : 0.f;
      for (int j = tid * (NB1 / T); j < bstar; j++) { ca2 += (int)s_cnt[j]; ea2 += s_esum[j]; }
      s_accA = ca2; s_accE = ea2;
    }
  }
  __syncthreads();
  const int bstar = s_bstar;
  const float thresh = s_thresh;

  // ---- pass 2: gather coarse boundary-bin candidates ----
  {
    auto proc = [&](float t, int v0) {
      if (bin1_of(m, t) == bstar) {
        unsigned p = atomicAdd(&s_num, 1u);
        if (p < (unsigned)XCAP) { s_xl[p] = t; s_il[p] = v0; }
      }
    };
    for (int v0 = tid; v0 < VB; v0 += 4 * T) {
      proc(xr[v0], v0); proc(xr[v0 + T], v0 + T);
      proc(xr[v0 + 2 * T], v0 + 2 * T); proc(xr[v0 + 3 * T], v0 + 3 * T);
    }
    for (int v0 = VB + tid; v0 < V; v0 += T) proc(xr[v0], v0);
  }
  __syncthreads();
  const int M1 = (int)(s_num < (unsigned)XCAP ? s_num : (unsigned)XCAP);
  const float hi2 = hi2_of(m, bstar);

  // ---- fine histogram over gathered candidates (LDS only) ----
  for (int i = tid; i < NB2; i += T) { s_cnt[i] = 0u; s_esum[i] = 0.f; }
  __syncthreads();
  for (int i = tid; i < M1; i += T) {
    float t = s_xl[i];
    int b2 = bin2_of(hi2, t);
    atomicAdd(&s_esum[b2], __expf(t - m));
    atomicAdd(&s_cnt[b2], 1u);
  }
  __syncthreads();
  {
    const int base = tid * (NB2 / T);
    unsigned pc = 0; float pe = 0.f;
#pragma unroll
    for (int j = 0; j < NB2 / T; j++) { pc += s_cnt[base + j]; pe += s_esum[base + j]; }
    s_pc[tid] = pc; s_pe[tid] = pe;
    __syncthreads();
    for (int off = 1; off < T; off <<= 1) {
      unsigned cp = 0; float ep = 0.f;
      if (tid >= off) { cp = s_pc[tid - off]; ep = s_pe[tid - off]; }
      __syncthreads();
      s_pc[tid] += cp; s_pe[tid] += ep;
      __syncthreads();
    }
    const int accA0 = s_accA; const float accE0 = s_accE;
    int ca = accA0 + (int)(tid ? s_pc[tid - 1] : 0u);
    float ea = accE0 + (tid ? s_pe[tid - 1] : 0.f);
    int found = NB2;
#pragma unroll
    for (int j = 0; j < NB2 / T; j++) {
      int cb = (int)s_cnt[base + j]; float eb = s_esum[base + j];
      if ((ca + cb > K) || (ea + eb > thresh)) { found = base + j; break; }
      ca += cb; ea += eb;
    }
    if (found < NB2) atomicMin(&s_fstar, found);
    __syncthreads();
    if (s_fstar == NB2 && tid == 0) s_fstar = NB2 - 1;   // fp-jitter fallback
    __syncthreads();
    const int fstar = s_fstar;
    if (tid == (fstar / (NB2 / T))) {
      int ca2 = accA0 + (int)(tid ? s_pc[tid - 1] : 0u);
      float ea2 = accE0 + (tid ? s_pe[tid - 1] : 0.f);
      for (int j = tid * (NB2 / T); j < fstar; j++) { ca2 += (int)s_cnt[j]; ea2 += s_esum[j]; }
      s_accA2 = ca2; s_accE2 = ea2;
    }
  }
  __syncthreads();
  const int fstar = s_fstar;

  // gather fine boundary-bin candidates from the list
  for (int i = tid; i < M1; i += T) {
    float t = s_xl[i];
    if (bin2_of(hi2, t) == fstar) {
      unsigned p = atomicAdd(&s_num2, 1u);
      if (p < (unsigned)XCAP2) { s_x2[p] = t; s_i2[p] = s_il[i]; }
    }
  }
  __syncthreads();

  // ---- exact walk in (value desc, index asc) order, exclusive tests ----
  if (tid == 0) {
    int M2 = (int)(s_num2 < (unsigned)XCAP2 ? s_num2 : (unsigned)XCAP2);
    int accA = s_accA2; float accE = s_accE2;
    float tstar = FLT_MAX; int istar = -1;
    for (;;) {
      float best = -FLT_MAX; int bidx = 0x7fffffff; bool found = false;
      for (int i = 0; i < M2; i++) {
        float xv = s_x2[i]; int iv = s_i2[i];
        bool after = (xv < tstar) || (xv == tstar && iv > istar);
        if (!after) continue;
        if (!found || xv > best || (xv == best && iv < bidx)) {
          best = xv; bidx = iv; found = true;
        }
      }
      if (!found) break;
      if (accA < K && accE <= thresh) {
        accA++; accE += __expf(best - m);
        tstar = best; istar = bidx;
      } else break;
    }
    RowStats st;
    st.m = m; st.tstar = tstar; st.Z = accE;
    st.bstar = bstar; st.fstar = fstar; st.istar = istar;
    st.pad[0] = st.pad[1] = 0;
    stats[n] = st;
  }
}

// ---------------- final: in-place masked softmax ----------------
__global__ __launch_bounds__(256)
void sampler_final(float* __restrict__ buf, const RowStats* __restrict__ stats)
{
  int n = blockIdx.y;
  int v = blockIdx.x * 256 + threadIdx.x;
  if (v >= V) return;
  RowStats st = stats[n];
  float x = buf[(size_t)n * V + v];
  int b = bin1_of(st.m, x);
  bool kept;
  if (b < st.bstar) kept = true;
  else if (b > st.bstar) kept = false;
  else {
    float hi2 = hi2_of(st.m, st.bstar);
    int b2 = bin2_of(hi2, x);
    kept = (b2 < st.fstar) ||
           (b2 == st.fstar && (x > st.tstar || (x == st.tstar && v <= st.istar)));
  }
  buf[(size_t)n * V + v] = kept ? (__expf(x - st.m) / st.Z) : 0.f;
}

extern "C" void kernel_launch(void* const* d_in, const int* in_sizes, int n_in,
                              void* d_out, int out_size, void* d_ws, size_t ws_size,
                              hipStream_t stream) {
  const float* hs    = (const float*)d_in[0];
  const float* emb   = (const float*)d_in[1];
  const int*   toks  = (const int*)d_in[2];
  const float* pres  = (const float*)d_in[3];
  const float* freq  = (const float*)d_in[4];
  const float* rep   = (const float*)d_in[5];
  const float* temps = (const float*)d_in[6];
  const float* tps   = (const float*)d_in[7];
  const int*   tks   = (const int*)d_in[8];
  float* out = (float*)d_out;

  char* ws = (char*)d_ws;
  RowStats* stats = (RowStats*)ws;                        // 4 KB
  ushort* Apk = (ushort*)(ws + 8192);                     // 2 MB packed+swizzled A

  sampler_prep  <<<dim3(NSTEP * 1024 / 256),  dim3(256), 0, stream>>>(hs, Apk);
  sampler_gemm  <<<dim3((V + BN - 1) / BN),   dim3(256), 0, stream>>>(Apk, emb, temps, out);
  sampler_fixup <<<dim3(N),                   dim3(256), 0, stream>>>(out, toks, pres, freq, rep, temps);
  sampler_select<<<dim3(N),                   dim3(512), 0, stream>>>(out, tps, tks, stats);
  sampler_final <<<dim3((V + 255) / 256, N),  dim3(256), 0, stream>>>(out, stats);
}

// Round 2
// 1288.659 us; speedup vs baseline: 1.6353x; 1.0241x over previous
//
#include <hip/hip_runtime.h>
#include <math.h>
#include <float.h>

constexpr int N = 128;
constexpr int V = 50257;
constexpr int H = 4096;
constexpr int L = 200;

// ---------------- GEMM tiling ----------------
constexpr int BN = 64;            // v-cols per block
constexpr int BK = 32;            // k per step
constexpr int NSTEP = H / BK;     // 128
// LDS per buffer: A tile 128x32 (hi+lo bf16 interleaved, 8x16B chunks/row) = 16 KB
//                 B tile 64x32 f32 (8x16B chunks/row)                      =  8 KB
constexpr int A_BYTES = 16384;
constexpr int B_BYTES = 8192;
constexpr int BUF_BYTES = A_BYTES + B_BYTES;   // 24576; x3 = 72 KB -> 2 blocks/CU

constexpr int NB1 = 1024;             // coarse bins
constexpr int NB2 = 1024;             // fine bins (within boundary coarse bin)
constexpr float RANGE = 48.0f;        // covers (rowmax - logit) span with margin
constexpr float W1 = RANGE / (float)NB1;          // 0.046875 (exact)
constexpr float INV_W1 = (float)NB1 / RANGE;
constexpr float INV_W2 = (float)NB1 * (float)NB2 / RANGE;
constexpr int XCAP = 2048;            // coarse boundary-bin candidate capacity
constexpr int XCAP2 = 256;            // fine boundary-bin candidate capacity

using short8 = __attribute__((ext_vector_type(8))) short;  // 8 bf16
using f32x4  = __attribute__((ext_vector_type(4))) float;

struct RowStats { float m, tstar, Z; int bstar, fstar, istar; int pad[2]; };  // 32 B

// binning helpers -- MUST be bit-identical between select & final
__device__ __forceinline__ int bin1_of(float m, float x) {
  int b = (int)((m - x) * INV_W1);
  return b < 0 ? 0 : (b > NB1 - 1 ? NB1 - 1 : b);
}
__device__ __forceinline__ float hi2_of(float m, int bstar) {
  return __fmaf_rn((float)bstar, -W1, m);     // forced fma: identical in both kernels
}
__device__ __forceinline__ int bin2_of(float hi2, float x) {
  int b = (int)((hi2 - x) * INV_W2);
  return b < 0 ? 0 : (b > NB2 - 1 ? NB2 - 1 : b);
}

// async 16-B global -> LDS copy (wave-uniform LDS base + lane*16 by construction)
__device__ __forceinline__ void gl_lds16(const void* g, void* l) {
  __builtin_amdgcn_global_load_lds(
      (const __attribute__((address_space(1))) unsigned int*)g,
      (__attribute__((address_space(3))) unsigned int*)l, 16, 0, 0);
}

// ---------------- prep: write A as the pre-swizzled packed LDS image ----------------
// For k-step t (0..127), record idx (0..1023): row = idx>>3, chunk c = idx&7.
// LDS chunk c of row holds *global* chunk g = c ^ (row&7), where g<4 -> bf16-hi of
// A[row][t*32 + g*8 .. +8), g>=4 -> bf16-lo of A[row][t*32 + (g&3)*8 .. +8).
// GEMM staging of A is then a perfectly linear 16-B copy (rule #21 compliant).
__global__ __launch_bounds__(256)
void sampler_prep(const float* __restrict__ A, ushort* __restrict__ Apk)
{
  int gid = blockIdx.x * 256 + threadIdx.x;   // 0 .. NSTEP*1024-1
  int t   = gid >> 10;
  int idx = gid & 1023;
  int row = idx >> 3;
  int c   = idx & 7;
  int g   = c ^ (row & 7);
  const float* src = A + (size_t)row * H + t * BK + (g & 3) * 8;
  short8 o;
#pragma unroll
  for (int j = 0; j < 8; j++) {
    float x = src[j];
    uint b = __float_as_uint(x);
    if (g < 4) {
      o[j] = (short)(b >> 16);                            // truncated bf16 hi
    } else {
      float hif = __uint_as_float(b & 0xFFFF0000u);
      o[j] = (short)(__float_as_uint(x - hif) >> 16);     // bf16 lo (x - hi exact)
    }
  }
  *(short8*)(Apk + (size_t)gid * 8) = o;
}

// split 8 f32 -> bf16 hi/lo (truncation), identical math to prep
__device__ __forceinline__ void split8v(const f32x4& f0, const f32x4& f1,
                                        short8& hi, short8& lo) {
  float xx[8] = {f0[0], f0[1], f0[2], f0[3], f1[0], f1[1], f1[2], f1[3]};
#pragma unroll
  for (int j = 0; j < 8; j++) {
    uint bb = __float_as_uint(xx[j]);
    hi[j] = (short)(bb >> 16);
    float hif = __uint_as_float(bb & 0xFFFF0000u);
    lo[j] = (short)(__float_as_uint(xx[j] - hif) >> 16);
  }
}

// ---------------- GEMM: LDS triple-buffered, counted-vmcnt pipeline ----------------
// Block: 128(M) x 64(N), BK=32. 4 waves as 2M x 2N; wave tile 64x32 (4mt x 2nt).
// Split-bf16 fp32 emulation: (Ah+Al)(Bh+Bl) ~ AhBh + AhBl + AlBh (3 MFMAs/tile).
// T3+T4: 3 LDS buffers, 2 stages in flight across barriers; each stage = 6
// global_load_lds instrs/wave, so vmcnt(12) retires exactly stage t while
// stages t+1,t+2 stay in flight (never drain to 0 in the main loop).
// LDS rows are 128 B = 8 x 16B chunks, chunk-swizzled by XOR(row&7) so each
// quarter-wave's ds_read_b128 hits 8 distinct chunk slots (min-aliasing).
__global__ __launch_bounds__(256, 2)
void sampler_gemm(const ushort* __restrict__ Apk, const float* __restrict__ B,
                  const float* __restrict__ temps, float* __restrict__ out)
{
  __shared__ __align__(16) char lds[3][BUF_BYTES];

  const int tid  = threadIdx.x;
  const int wave = tid >> 6, lane = tid & 63;
  const int cc   = lane & 15, quad = lane >> 4;
  const int wm   = wave >> 1, wn = wave & 1;
  const int v0   = blockIdx.x * BN;
  const int s7   = cc & 7;

  // ---- staging sources (per-thread, constant except k-step advance) ----
  const ushort* aS = Apk + (size_t)tid * 8;          // + i*2048 + t*8192 (ushorts)
  const float* bS[2];
#pragma unroll
  for (int i = 0; i < 2; i++) {
    int idx = i * 256 + tid;
    int row = idx >> 3, ch = idx & 7;
    int vv = v0 + row; vv = vv < V ? vv : V - 1;     // clamp OOB rows of last block
    bS[i] = B + (size_t)vv * H + ((ch ^ (row & 7)) << 2);  // pre-swizzled source
  }

  // ---- LDS read offsets (swizzled); row&7 == cc&7 for all tiles (16 | tile strides)
  const int aHi = (wm * 64 + cc) * 128 + ((quad ^ s7) << 4);
  const int aLo = (wm * 64 + cc) * 128 + (((4 + quad) ^ s7) << 4);
  const int bO0 = A_BYTES + (wn * 32 + cc) * 128 + (((2 * quad) ^ s7) << 4);
  const int bO1 = A_BYTES + (wn * 32 + cc) * 128 + (((2 * quad + 1) ^ s7) << 4);

  f32x4 acc[4][2];
#pragma unroll
  for (int mt = 0; mt < 4; mt++)
#pragma unroll
    for (int nt = 0; nt < 2; nt++) acc[mt][nt] = (f32x4){0.f, 0.f, 0.f, 0.f};

  auto stage = [&](int t, int sl) {
    char* buf = lds[sl];
    const ushort* a = aS + (size_t)t * 8192;
#pragma unroll
    for (int i = 0; i < 4; i++)                       // A: 16 KB linear copy
      gl_lds16(a + i * 2048, buf + (i * 256 + tid) * 16);
#pragma unroll
    for (int i = 0; i < 2; i++)                       // B: 8 KB, source-swizzled
      gl_lds16(bS[i] + t * BK, buf + A_BYTES + (i * 256 + tid) * 16);
  };

  stage(0, 0);
  stage(1, 1);

  int sel = 0, seln = 2;
#pragma unroll 1
  for (int t = 0; t < NSTEP; ++t) {
    if (t + 2 < NSTEP) stage(t + 2, seln);            // keep 3 stages in flight

    // retire exactly stage t (own-wave count); barrier makes it block-wide
    if (t < NSTEP - 2)
      asm volatile("s_waitcnt vmcnt(12)" ::: "memory");
    else if (t == NSTEP - 2)
      asm volatile("s_waitcnt vmcnt(6)" ::: "memory");
    else
      asm volatile("s_waitcnt vmcnt(0)" ::: "memory");
    __builtin_amdgcn_s_barrier();

    const char* buf = lds[sel];
    short8 ah[4], al[4];
    f32x4 b0[2], b1[2];
#pragma unroll
    for (int mt = 0; mt < 4; mt++) {
      ah[mt] = *(const short8*)(buf + aHi + mt * 2048);
      al[mt] = *(const short8*)(buf + aLo + mt * 2048);
    }
#pragma unroll
    for (int nt = 0; nt < 2; nt++) {
      b0[nt] = *(const f32x4*)(buf + bO0 + nt * 2048);
      b1[nt] = *(const f32x4*)(buf + bO1 + nt * 2048);
    }
    short8 bh[2], bl[2];
#pragma unroll
    for (int nt = 0; nt < 2; nt++) split8v(b0[nt], b1[nt], bh[nt], bl[nt]);

#pragma unroll
    for (int mt = 0; mt < 4; mt++)
#pragma unroll
      for (int nt = 0; nt < 2; nt++) {
        acc[mt][nt] = __builtin_amdgcn_mfma_f32_16x16x32_bf16(ah[mt], bh[nt], acc[mt][nt], 0, 0, 0);
        acc[mt][nt] = __builtin_amdgcn_mfma_f32_16x16x32_bf16(ah[mt], bl[nt], acc[mt][nt], 0, 0, 0);
        acc[mt][nt] = __builtin_amdgcn_mfma_f32_16x16x32_bf16(al[mt], bh[nt], acc[mt][nt], 0, 0, 0);
      }
    // all waves done reading lds[sel] before next iteration's stage overwrites it
    __builtin_amdgcn_s_barrier();
    sel  = (sel  == 2) ? 0 : sel  + 1;
    seln = (seln == 2) ? 0 : seln + 1;
  }

  // ---- epilogue: C/D col=lane&15, row=quad*4+reg ----
#pragma unroll
  for (int mt = 0; mt < 4; mt++)
#pragma unroll
    for (int nt = 0; nt < 2; nt++) {
      int v = v0 + wn * 32 + nt * 16 + cc;
      if (v < V) {
#pragma unroll
        for (int r4 = 0; r4 < 4; r4++) {
          int r = wm * 64 + mt * 16 + quad * 4 + r4;
          out[(size_t)r * V + v] = acc[mt][nt][r4] / temps[r];
        }
      }
    }
}

// ---------------- penalties fixup (first-occurrence thread = unique writer) ----------
__global__ __launch_bounds__(256)
void sampler_fixup(float* __restrict__ logits, const int* __restrict__ toks,
                   const float* __restrict__ pres, const float* __restrict__ freq,
                   const float* __restrict__ rep, const float* __restrict__ temps)
{
  int n = blockIdx.x, l = threadIdx.x;
  if (l >= L) return;
  const int* row = toks + n * L;
  int tok = row[l];
  for (int j = 0; j < l; j++)
    if (row[j] == tok) return;
  int cnum = 0;
  for (int j = 0; j < L; j++) cnum += (row[j] == tok) ? 1 : 0;
  float T = temps[n];
  float x = logits[(size_t)n * V + tok];
  float rp = rep[n];
  x = (x > 0.f) ? (x / rp) : (x * rp);
  x -= (freq[n] * (float)cnum + pres[n]) / T;
  logits[(size_t)n * V + tok] = x;
}

// ---------------- select: rowmax + 2-level hist select + exact tie walk -------------
// 512 threads (2 waves/SIMD), 4-way batched global loads for latency hiding.
__global__ __launch_bounds__(512)
void sampler_select(const float* __restrict__ logits, const float* __restrict__ top_ps,
                    const int* __restrict__ top_ks, RowStats* __restrict__ stats)
{
  const int n = blockIdx.x, tid = threadIdx.x;
  const float* __restrict__ xr = logits + (size_t)n * V;
  constexpr int T = 512;
  constexpr int VB = (V / (4 * T)) * (4 * T);   // 49152

  __shared__ unsigned s_cnt[NB1];
  __shared__ float s_esum[NB1];
  __shared__ unsigned s_pc[T];
  __shared__ float s_pe[T];
  __shared__ float s_xl[XCAP];
  __shared__ int s_il[XCAP];
  __shared__ float s_x2[XCAP2];
  __shared__ int s_i2[XCAP2];
  __shared__ int s_bstar, s_fstar;
  __shared__ int s_accA, s_accA2;
  __shared__ float s_accE, s_accE2;
  __shared__ unsigned s_num, s_num2;
  __shared__ float s_m, s_thresh;

  const float P = top_ps[n];
  const int K = top_ks[n];

  // ---- pass 0: row max ----
  float mx = -FLT_MAX;
  for (int v0 = tid; v0 < VB; v0 += 4 * T) {
    float t0 = xr[v0], t1 = xr[v0 + T], t2 = xr[v0 + 2 * T], t3 = xr[v0 + 3 * T];
    mx = fmaxf(mx, fmaxf(fmaxf(t0, t1), fmaxf(t2, t3)));
  }
  for (int v0 = VB + tid; v0 < V; v0 += T) mx = fmaxf(mx, xr[v0]);
  s_pe[tid] = mx; __syncthreads();
  for (int s = T / 2; s > 0; s >>= 1) {
    if (tid < s) s_pe[tid] = fmaxf(s_pe[tid], s_pe[tid + s]);
    __syncthreads();
  }
  if (tid == 0) s_m = s_pe[0];
  __syncthreads();
  const float m = s_m;

  for (int i = tid; i < NB1; i += T) { s_cnt[i] = 0u; s_esum[i] = 0.f; }
  if (tid == 0) { s_bstar = NB1; s_fstar = NB2; s_num = 0u; s_num2 = 0u; }
  __syncthreads();

  // ---- pass 1: coarse histogram (count + expsum) ----
  {
    auto proc = [&](float t) {
      int b = bin1_of(m, t);
      atomicAdd(&s_esum[b], __expf(t - m));
      atomicAdd(&s_cnt[b], 1u);
    };
    for (int v0 = tid; v0 < VB; v0 += 4 * T) {
      float t0 = xr[v0], t1 = xr[v0 + T], t2 = xr[v0 + 2 * T], t3 = xr[v0 + 3 * T];
      proc(t0); proc(t1); proc(t2); proc(t3);
    }
    for (int v0 = VB + tid; v0 < V; v0 += T) proc(xr[v0]);
  }
  __syncthreads();

  // inclusive prefix over NB1 bins: 2 bins/thread + T-wide scan
  {
    const int base = tid * (NB1 / T);
    unsigned pc = 0; float pe = 0.f;
#pragma unroll
    for (int j = 0; j < NB1 / T; j++) { pc += s_cnt[base + j]; pe += s_esum[base + j]; }
    s_pc[tid] = pc; s_pe[tid] = pe;
    __syncthreads();
    for (int off = 1; off < T; off <<= 1) {
      unsigned cp = 0; float ep = 0.f;
      if (tid >= off) { cp = s_pc[tid - off]; ep = s_pe[tid - off]; }
      __syncthreads();
      s_pc[tid] += cp; s_pe[tid] += ep;
      __syncthreads();
    }
    if (tid == 0) s_thresh = P * s_pe[T - 1];
    __syncthreads();
    const float thresh = s_thresh;

    // first bin where inclusive count > K or inclusive expsum > thresh (monotone)
    int ca = (int)(tid ? s_pc[tid - 1] : 0u);
    float ea = tid ? s_pe[tid - 1] : 0.f;
    int found = NB1;
#pragma unroll
    for (int j = 0; j < NB1 / T; j++) {
      int cb = (int)s_cnt[base + j]; float eb = s_esum[base + j];
      if ((ca + cb > K) || (ea + eb > thresh)) { found = base + j; break; }
      ca += cb; ea += eb;
    }
    if (found < NB1) atomicMin(&s_bstar, found);
    __syncthreads();
    const int bstar = s_bstar;      // always < NB1 (count at last bin = V > K)
    if (tid == (bstar / (NB1 / T))) {
      int ca2 = (int)(tid ? s_pc[tid - 1] : 0u);
      float ea2 = tid ? s_pe[tid - 1] : 0.f;
      for (int j = tid * (NB1 / T); j < bstar; j++) { ca2 += (int)s_cnt[j]; ea2 += s_esum[j]; }
      s_accA = ca2; s_accE = ea2;
    }
  }
  __syncthreads();
  const int bstar = s_bstar;
  const float thresh = s_thresh;

  // ---- pass 2: gather coarse boundary-bin candidates ----
  {
    auto proc = [&](float t, int v0) {
      if (bin1_of(m, t) == bstar) {
        unsigned p = atomicAdd(&s_num, 1u);
        if (p < (unsigned)XCAP) { s_xl[p] = t; s_il[p] = v0; }
      }
    };
    for (int v0 = tid; v0 < VB; v0 += 4 * T) {
      proc(xr[v0], v0); proc(xr[v0 + T], v0 + T);
      proc(xr[v0 + 2 * T], v0 + 2 * T); proc(xr[v0 + 3 * T], v0 + 3 * T);
    }
    for (int v0 = VB + tid; v0 < V; v0 += T) proc(xr[v0], v0);
  }
  __syncthreads();
  const int M1 = (int)(s_num < (unsigned)XCAP ? s_num : (unsigned)XCAP);
  const float hi2 = hi2_of(m, bstar);

  // ---- fine histogram over gathered candidates (LDS only) ----
  for (int i = tid; i < NB2; i += T) { s_cnt[i] = 0u; s_esum[i] = 0.f; }
  __syncthreads();
  for (int i = tid; i < M1; i += T) {
    float t = s_xl[i];
    int b2 = bin2_of(hi2, t);
    atomicAdd(&s_esum[b2], __expf(t - m));
    atomicAdd(&s_cnt[b2], 1u);
  }
  __syncthreads();
  {
    const int base = tid * (NB2 / T);
    unsigned pc = 0; float pe = 0.f;
#pragma unroll
    for (int j = 0; j < NB2 / T; j++) { pc += s_cnt[base + j]; pe += s_esum[base + j]; }
    s_pc[tid] = pc; s_pe[tid] = pe;
    __syncthreads();
    for (int off = 1; off < T; off <<= 1) {
      unsigned cp = 0; float ep = 0.f;
      if (tid >= off) { cp = s_pc[tid - off]; ep = s_pe[tid - off]; }
      __syncthreads();
      s_pc[tid] += cp; s_pe[tid] += ep;
      __syncthreads();
    }
    const int accA0 = s_accA; const float accE0 = s_accE;
    int ca = accA0 + (int)(tid ? s_pc[tid - 1] : 0u);
    float ea = accE0 + (tid ? s_pe[tid - 1] : 0.f);
    int found = NB2;
#pragma unroll
    for (int j = 0; j < NB2 / T; j++) {
      int cb = (int)s_cnt[base + j]; float eb = s_esum[base + j];
      if ((ca + cb > K) || (ea + eb > thresh)) { found = base + j; break; }
      ca += cb; ea += eb;
    }
    if (found < NB2) atomicMin(&s_fstar, found);
    __syncthreads();
    if (s_fstar == NB2 && tid == 0) s_fstar = NB2 - 1;   // fp-jitter fallback
    __syncthreads();
    const int fstar = s_fstar;
    if (tid == (fstar / (NB2 / T))) {
      int ca2 = accA0 + (int)(tid ? s_pc[tid - 1] : 0u);
      float ea2 = accE0 + (tid ? s_pe[tid - 1] : 0.f);
      for (int j = tid * (NB2 / T); j < fstar; j++) { ca2 += (int)s_cnt[j]; ea2 += s_esum[j]; }
      s_accA2 = ca2; s_accE2 = ea2;
    }
  }
  __syncthreads();
  const int fstar = s_fstar;

  // gather fine boundary-bin candidates from the list
  for (int i = tid; i < M1; i += T) {
    float t = s_xl[i];
    if (bin2_of(hi2, t) == fstar) {
      unsigned p = atomicAdd(&s_num2, 1u);
      if (p < (unsigned)XCAP2) { s_x2[p] = t; s_i2[p] = s_il[i]; }
    }
  }
  __syncthreads();

  // ---- exact walk in (value desc, index asc) order, exclusive tests ----
  if (tid == 0) {
    int M2 = (int)(s_num2 < (unsigned)XCAP2 ? s_num2 : (unsigned)XCAP2);
    int accA = s_accA2; float accE = s_accE2;
    float tstar = FLT_MAX; int istar = -1;
    for (;;) {
      float best = -FLT_MAX; int bidx = 0x7fffffff; bool found = false;
      for (int i = 0; i < M2; i++) {
        float xv = s_x2[i]; int iv = s_i2[i];
        bool after = (xv < tstar) || (xv == tstar && iv > istar);
        if (!after) continue;
        if (!found || xv > best || (xv == best && iv < bidx)) {
          best = xv; bidx = iv; found = true;
        }
      }
      if (!found) break;
      if (accA < K && accE <= thresh) {
        accA++; accE += __expf(best - m);
        tstar = best; istar = bidx;
      } else break;
    }
    RowStats st;
    st.m = m; st.tstar = tstar; st.Z = accE;
    st.bstar = bstar; st.fstar = fstar; st.istar = istar;
    st.pad[0] = st.pad[1] = 0;
    stats[n] = st;
  }
}

// ---------------- final: in-place masked softmax ----------------
__global__ __launch_bounds__(256)
void sampler_final(float* __restrict__ buf, const RowStats* __restrict__ stats)
{
  int n = blockIdx.y;
  int v = blockIdx.x * 256 + threadIdx.x;
  if (v >= V) return;
  RowStats st = stats[n];
  float x = buf[(size_t)n * V + v];
  int b = bin1_of(st.m, x);
  bool kept;
  if (b < st.bstar) kept = true;
  else if (b > st.bstar) kept = false;
  else {
    float hi2 = hi2_of(st.m, st.bstar);
    int b2 = bin2_of(hi2, x);
    kept = (b2 < st.fstar) ||
           (b2 == st.fstar && (x > st.tstar || (x == st.tstar && v <= st.istar)));
  }
  buf[(size_t)n * V + v] = kept ? (__expf(x - st.m) / st.Z) : 0.f;
}

extern "C" void kernel_launch(void* const* d_in, const int* in_sizes, int n_in,
                              void* d_out, int out_size, void* d_ws, size_t ws_size,
                              hipStream_t stream) {
  const float* hs    = (const float*)d_in[0];
  const float* emb   = (const float*)d_in[1];
  const int*   toks  = (const int*)d_in[2];
  const float* pres  = (const float*)d_in[3];
  const float* freq  = (const float*)d_in[4];
  const float* rep   = (const float*)d_in[5];
  const float* temps = (const float*)d_in[6];
  const float* tps   = (const float*)d_in[7];
  const int*   tks   = (const int*)d_in[8];
  float* out = (float*)d_out;

  char* ws = (char*)d_ws;
  RowStats* stats = (RowStats*)ws;                        // 4 KB
  ushort* Apk = (ushort*)(ws + 8192);                     // 2 MB packed+swizzled A

  sampler_prep  <<<dim3(NSTEP * 1024 / 256),  dim3(256), 0, stream>>>(hs, Apk);
  sampler_gemm  <<<dim3((V + BN - 1) / BN),   dim3(256), 0, stream>>>(Apk, emb, temps, out);
  sampler_fixup <<<dim3(N),                   dim3(256), 0, stream>>>(out, toks, pres, freq, rep, temps);
  sampler_select<<<dim3(N),                   dim3(512), 0, stream>>>(out, tps, tks, stats);
  sampler_final <<<dim3((V + 255) / 256, N),  dim3(256), 0, stream>>>(out, stats);
}